// Round 3
// baseline (3100.693 us; speedup 1.0000x reference)
//
#include <hip/hip_runtime.h>

#define D_IN  128
#define D_HID 128
#define D_OUT 64

// ---------------------------------------------------------------------------
// deg[n] = number of edges with dst == n (computed once; reused by both layers)
// ---------------------------------------------------------------------------
__global__ void deg_kernel(const int* __restrict__ dst, float* __restrict__ deg, int E) {
    int e = blockIdx.x * blockDim.x + threadIdx.x;
    if (e < E) atomicAdd(&deg[dst[e]], 1.0f);
}

// ---------------------------------------------------------------------------
// Scatter-add of 128-wide feature rows: agg[dst[e]] += feat[src[e]]
// thread t -> edge e = t/32, feature chunk c = (t%32)*4 (float4 per thread).
// Consecutive lanes cover consecutive features of one edge -> coalesced gather.
// ---------------------------------------------------------------------------
__global__ void scatter_d128(const float* __restrict__ feat, const int* __restrict__ src,
                             const int* __restrict__ dst, float* __restrict__ agg, int E) {
    long t = (long)blockIdx.x * blockDim.x + threadIdx.x;
    int e = (int)(t >> 5);
    if (e >= E) return;
    int c = ((int)t & 31) << 2;
    int s = src[e];
    int d = dst[e];
    const float4 v = *(const float4*)(feat + (long)s * 128 + c);
    float* a = agg + (long)d * 128 + c;
    atomicAdd(a + 0, v.x);
    atomicAdd(a + 1, v.y);
    atomicAdd(a + 2, v.z);
    atomicAdd(a + 3, v.w);
}

// ---------------------------------------------------------------------------
// Fused SAGE linear: out[i][j] = (agg[i]/max(deg,1)) @ Wl + xin[i] @ Wr + b
// One thread -> 4 output columns of one row. Wl/Wr column loads are float4 and
// coalesced across lanes; agg/x row reads are wave-broadcast (same address).
// ---------------------------------------------------------------------------
template<int K, int M, bool RELU>
__global__ void sage_linear(const float* __restrict__ agg, const float* __restrict__ deg,
                            const float* __restrict__ xin,
                            const float* __restrict__ Wl, const float* __restrict__ Wr,
                            const float* __restrict__ bias, float* __restrict__ out, int N) {
    constexpr int JPR = M / 4;                 // threads per row
    long t = (long)blockIdx.x * blockDim.x + threadIdx.x;
    long i = t / JPR;
    if (i >= N) return;
    int j = ((int)(t % JPR)) << 2;

    float inv = 1.0f / fmaxf(deg[i], 1.0f);
    float4 acc = *(const float4*)(bias + j);
    const float* ai = agg + i * K;
    const float* xi = xin + i * K;

    #pragma unroll 4
    for (int k = 0; k < K; ++k) {
        float m  = ai[k] * inv;
        float xv = xi[k];
        float4 wl = *(const float4*)(Wl + (long)k * M + j);
        float4 wr = *(const float4*)(Wr + (long)k * M + j);
        acc.x = fmaf(m, wl.x, fmaf(xv, wr.x, acc.x));
        acc.y = fmaf(m, wl.y, fmaf(xv, wr.y, acc.y));
        acc.z = fmaf(m, wl.z, fmaf(xv, wr.z, acc.z));
        acc.w = fmaf(m, wl.w, fmaf(xv, wr.w, acc.w));
    }
    if (RELU) {
        acc.x = fmaxf(acc.x, 0.0f);
        acc.y = fmaxf(acc.y, 0.0f);
        acc.z = fmaxf(acc.z, 0.0f);
        acc.w = fmaxf(acc.w, 0.0f);
    }
    *(float4*)(out + i * M + j) = acc;
}

extern "C" void kernel_launch(void* const* d_in, const int* in_sizes, int n_in,
                              void* d_out, int out_size, void* d_ws, size_t ws_size,
                              hipStream_t stream) {
    const float* x   = (const float*)d_in[0];   // [N, 128]
    const int*   ei  = (const int*)  d_in[1];   // [2, E]
    const float* W1l = (const float*)d_in[2];   // [128, 128]
    const float* W1r = (const float*)d_in[3];   // [128, 128]
    const float* b1  = (const float*)d_in[4];   // [128]
    const float* W2l = (const float*)d_in[5];   // [128, 64]
    const float* W2r = (const float*)d_in[6];   // [128, 64]
    const float* b2  = (const float*)d_in[7];   // [64]
    float* out = (float*)d_out;                 // [N, 64]

    const int N = in_sizes[0] / D_IN;
    const int E = in_sizes[1] / 2;
    const int* src = ei;        // edge_index[0]
    const int* dst = ei + E;    // edge_index[1]

    // workspace layout: agg [N*128] | h [N*128] | deg [N]   (~51.4 MB)
    float* agg = (float*)d_ws;
    float* h   = agg + (size_t)N * D_HID;
    float* deg = h   + (size_t)N * D_HID;

    // ---- degree (once) ----
    hipMemsetAsync(deg, 0, (size_t)N * sizeof(float), stream);
    deg_kernel<<<(E + 255) / 256, 256, 0, stream>>>(dst, deg, E);

    // ---- layer 1: aggregate x, then h = relu(mean@W1_l + x@W1_r + b1) ----
    hipMemsetAsync(agg, 0, (size_t)N * D_IN * sizeof(float), stream);
    {
        long T = (long)E * 32;
        scatter_d128<<<(int)((T + 255) / 256), 256, 0, stream>>>(x, src, dst, agg, E);
    }
    {
        long T = (long)N * (D_HID / 4);
        sage_linear<D_IN, D_HID, true>
            <<<(int)((T + 255) / 256), 256, 0, stream>>>(agg, deg, x, W1l, W1r, b1, h, N);
    }

    // ---- layer 2: aggregate h, then out = mean@W2_l + h@W2_r + b2 ----
    hipMemsetAsync(agg, 0, (size_t)N * D_HID * sizeof(float), stream);
    {
        long T = (long)E * 32;
        scatter_d128<<<(int)((T + 255) / 256), 256, 0, stream>>>(h, src, dst, agg, E);
    }
    {
        long T = (long)N * (D_OUT / 4);
        sage_linear<D_HID, D_OUT, false>
            <<<(int)((T + 255) / 256), 256, 0, stream>>>(agg, deg, h, W2l, W2r, b2, out, N);
    }
}

// Round 4
// 605.192 us; speedup vs baseline: 5.1235x; 5.1235x over previous
//
#include <hip/hip_runtime.h>

#define D_IN  128
#define D_HID 128
#define D_OUT 64

// ---------------------------------------------------------------------------
// CSR build step 1: cnt[n] = in-degree of node n
// ---------------------------------------------------------------------------
__global__ void hist_kernel(const int* __restrict__ dst, int* __restrict__ cnt, int E) {
    int e = blockIdx.x * blockDim.x + threadIdx.x;
    if (e < E) atomicAdd(&cnt[dst[e]], 1);
}

// ---------------------------------------------------------------------------
// CSR build step 2: exclusive scan of cnt -> rp[0..N], cursor = copy of rp.
// Single block of 1024 threads, each owns a contiguous chunk (~49 elems).
// ---------------------------------------------------------------------------
__global__ void scan_kernel(const int* __restrict__ cnt, int* __restrict__ rp,
                            int* __restrict__ cursor, int N) {
    __shared__ int sums[1024];
    const int t = threadIdx.x;
    const int chunk = (N + 1023) / 1024;
    const int lo = t * chunk;
    const int hi = min(lo + chunk, N);
    int s = 0;
    for (int i = lo; i < hi; ++i) s += cnt[i];
    sums[t] = s;
    __syncthreads();
    // Hillis-Steele inclusive scan over 1024 partial sums
    for (int off = 1; off < 1024; off <<= 1) {
        int v = (t >= off) ? sums[t - off] : 0;
        __syncthreads();
        sums[t] += v;
        __syncthreads();
    }
    int run = (t > 0) ? sums[t - 1] : 0;   // exclusive prefix of this chunk
    for (int i = lo; i < hi; ++i) {
        int c = cnt[i];
        rp[i] = run;
        cursor[i] = run;
        run += c;
    }
    if (t == 0) rp[N] = sums[1023];        // total == E
}

// ---------------------------------------------------------------------------
// CSR build step 3: col[slot] = src[e], slot handed out by per-dst cursor.
// ---------------------------------------------------------------------------
__global__ void fill_kernel(const int* __restrict__ src, const int* __restrict__ dst,
                            int* __restrict__ cursor, int* __restrict__ col, int E) {
    int e = blockIdx.x * blockDim.x + threadIdx.x;
    if (e < E) {
        int slot = atomicAdd(&cursor[dst[e]], 1);
        col[slot] = src[e];
    }
}

// ---------------------------------------------------------------------------
// Dual linear: outl = xin @ Wl, outr = xin @ Wr + b.  One thread -> 4 output
// cols of one row for BOTH products (x row value reused for 8 FMAs/iter).
// ---------------------------------------------------------------------------
template<int K, int M>
__global__ void dual_linear(const float* __restrict__ xin,
                            const float* __restrict__ Wl, const float* __restrict__ Wr,
                            const float* __restrict__ bias,
                            float* __restrict__ outl, float* __restrict__ outr, int N) {
    constexpr int JPR = M / 4;
    long t = (long)blockIdx.x * blockDim.x + threadIdx.x;
    long i = t / JPR;
    if (i >= N) return;
    int j = ((int)(t % JPR)) << 2;

    float4 accl = {0.f, 0.f, 0.f, 0.f};
    float4 accr = *(const float4*)(bias + j);
    const float* xi = xin + i * K;

    #pragma unroll 4
    for (int k = 0; k < K; ++k) {
        float xv = xi[k];
        float4 wl = *(const float4*)(Wl + (long)k * M + j);
        float4 wr = *(const float4*)(Wr + (long)k * M + j);
        accl.x = fmaf(xv, wl.x, accl.x);
        accl.y = fmaf(xv, wl.y, accl.y);
        accl.z = fmaf(xv, wl.z, accl.z);
        accl.w = fmaf(xv, wl.w, accl.w);
        accr.x = fmaf(xv, wr.x, accr.x);
        accr.y = fmaf(xv, wr.y, accr.y);
        accr.z = fmaf(xv, wr.z, accr.z);
        accr.w = fmaf(xv, wr.w, accr.w);
    }
    *(float4*)(outl + i * M + j) = accl;
    *(float4*)(outr + i * M + j) = accr;
}

// ---------------------------------------------------------------------------
// Gather aggregation: out[i] = act( (1/max(deg,1)) * sum_{s in nbr(i)} gl[s]
//                                   + rr[i] )
// Group of M/4 lanes per node, float4 per lane; neighbor loop 2x unrolled.
// ---------------------------------------------------------------------------
template<int M, bool RELU>
__global__ void gather_agg(const float* __restrict__ gl, const float* __restrict__ rr,
                           const int* __restrict__ rp, const int* __restrict__ col,
                           float* __restrict__ out, int N) {
    constexpr int G = M / 4;
    long t = (long)blockIdx.x * blockDim.x + threadIdx.x;
    long i = t / G;
    if (i >= N) return;
    int c = ((int)(t % G)) << 2;

    int beg = rp[i], end = rp[i + 1];
    float4 acc = {0.f, 0.f, 0.f, 0.f};
    int e = beg;
    for (; e + 1 < end; e += 2) {
        int s0 = col[e], s1 = col[e + 1];
        float4 v0 = *(const float4*)(gl + (long)s0 * M + c);
        float4 v1 = *(const float4*)(gl + (long)s1 * M + c);
        acc.x += v0.x + v1.x;
        acc.y += v0.y + v1.y;
        acc.z += v0.z + v1.z;
        acc.w += v0.w + v1.w;
    }
    if (e < end) {
        int s0 = col[e];
        float4 v0 = *(const float4*)(gl + (long)s0 * M + c);
        acc.x += v0.x; acc.y += v0.y; acc.z += v0.z; acc.w += v0.w;
    }

    float inv = 1.0f / fmaxf((float)(end - beg), 1.0f);
    float4 r = *(const float4*)(rr + i * M + c);
    float4 o;
    o.x = fmaf(acc.x, inv, r.x);
    o.y = fmaf(acc.y, inv, r.y);
    o.z = fmaf(acc.z, inv, r.z);
    o.w = fmaf(acc.w, inv, r.w);
    if (RELU) {
        o.x = fmaxf(o.x, 0.f); o.y = fmaxf(o.y, 0.f);
        o.z = fmaxf(o.z, 0.f); o.w = fmaxf(o.w, 0.f);
    }
    *(float4*)(out + i * M + c) = o;
}

extern "C" void kernel_launch(void* const* d_in, const int* in_sizes, int n_in,
                              void* d_out, int out_size, void* d_ws, size_t ws_size,
                              hipStream_t stream) {
    const float* x   = (const float*)d_in[0];   // [N, 128]
    const int*   ei  = (const int*)  d_in[1];   // [2, E]
    const float* W1l = (const float*)d_in[2];   // [128, 128]
    const float* W1r = (const float*)d_in[3];   // [128, 128]
    const float* b1  = (const float*)d_in[4];   // [128]
    const float* W2l = (const float*)d_in[5];   // [128, 64]
    const float* W2r = (const float*)d_in[6];   // [128, 64]
    const float* b2  = (const float*)d_in[7];   // [64]
    float* out = (float*)d_out;                 // [N, 64]

    const int N = in_sizes[0] / D_IN;
    const int E = in_sizes[1] / 2;
    const int* src = ei;        // edge_index[0]
    const int* dst = ei + E;    // edge_index[1]

    // -------- workspace layout --------
    // bufA [N*128] f32 : xl; later hl (first N*64) and hr (second N*64)
    // bufB [N*128] f32 : xr -> h (in-place)
    // rp   [N+1]   int | cnt [N] int | cursor [N] int | col [E] int
    float* bufA = (float*)d_ws;
    float* bufB = bufA + (size_t)N * D_HID;
    int*   rp     = (int*)(bufB + (size_t)N * D_HID);
    int*   cnt    = rp + (N + 1);
    int*   cursor = cnt + N;
    int*   col    = cursor + N;

    // -------- CSR build (per call; cheap int atomics) --------
    hipMemsetAsync(cnt, 0, (size_t)N * sizeof(int), stream);
    hist_kernel<<<(E + 255) / 256, 256, 0, stream>>>(dst, cnt, E);
    scan_kernel<<<1, 1024, 0, stream>>>(cnt, rp, cursor, N);
    fill_kernel<<<(E + 255) / 256, 256, 0, stream>>>(src, dst, cursor, col, E);

    // -------- layer 1 --------
    {   // xl = x@W1_l, xr = x@W1_r + b1
        long T = (long)N * (D_HID / 4);
        dual_linear<D_IN, D_HID>
            <<<(int)((T + 255) / 256), 256, 0, stream>>>(x, W1l, W1r, b1, bufA, bufB, N);
    }
    {   // h = relu(mean_gather(xl) + xr)   (h overwrites xr in place)
        long T = (long)N * (D_HID / 4);
        gather_agg<D_HID, true>
            <<<(int)((T + 255) / 256), 256, 0, stream>>>(bufA, bufB, rp, col, bufB, N);
    }

    // -------- layer 2 --------
    float* hl = bufA;                    // [N, 64]
    float* hr = bufA + (size_t)N * D_OUT; // [N, 64]
    {   // hl = h@W2_l, hr = h@W2_r + b2
        long T = (long)N * (D_OUT / 4);
        dual_linear<D_HID, D_OUT>
            <<<(int)((T + 255) / 256), 256, 0, stream>>>(bufB, W2l, W2r, b2, hl, hr, N);
    }
    {   // out = mean_gather(hl) + hr
        long T = (long)N * (D_OUT / 4);
        gather_agg<D_OUT, false>
            <<<(int)((T + 255) / 256), 256, 0, stream>>>(hl, hr, rp, col, out, N);
    }
}

// Round 5
// 378.662 us; speedup vs baseline: 8.1886x; 1.5982x over previous
//
#include <hip/hip_runtime.h>

#define D_IN  128
#define D_HID 128
#define D_OUT 64

// ---------------------------------------------------------------------------
// CSR build step 1: cnt[n] = in-degree of node n
// ---------------------------------------------------------------------------
__global__ void hist_kernel(const int* __restrict__ dst, int* __restrict__ cnt, int E) {
    int e = blockIdx.x * blockDim.x + threadIdx.x;
    if (e < E) atomicAdd(&cnt[dst[e]], 1);
}

// ---------------------------------------------------------------------------
// CSR build step 2: exclusive scan of cnt -> rp[0..N], cursor = copy of rp.
// Single block of 1024 threads, each owns a contiguous chunk (~49 elems).
// ---------------------------------------------------------------------------
__global__ void scan_kernel(const int* __restrict__ cnt, int* __restrict__ rp,
                            int* __restrict__ cursor, int N) {
    __shared__ int sums[1024];
    const int t = threadIdx.x;
    const int chunk = (N + 1023) / 1024;
    const int lo = t * chunk;
    const int hi = min(lo + chunk, N);
    int s = 0;
    for (int i = lo; i < hi; ++i) s += cnt[i];
    sums[t] = s;
    __syncthreads();
    for (int off = 1; off < 1024; off <<= 1) {
        int v = (t >= off) ? sums[t - off] : 0;
        __syncthreads();
        sums[t] += v;
        __syncthreads();
    }
    int run = (t > 0) ? sums[t - 1] : 0;
    for (int i = lo; i < hi; ++i) {
        int c = cnt[i];
        rp[i] = run;
        cursor[i] = run;
        run += c;
    }
    if (t == 0) rp[N] = sums[1023];
}

// ---------------------------------------------------------------------------
// CSR build step 3: col[slot] = src[e], slot handed out by per-dst cursor.
// ---------------------------------------------------------------------------
__global__ void fill_kernel(const int* __restrict__ src, const int* __restrict__ dst,
                            int* __restrict__ cursor, int* __restrict__ col, int E) {
    int e = blockIdx.x * blockDim.x + threadIdx.x;
    if (e < E) {
        int slot = atomicAdd(&cursor[dst[e]], 1);
        col[slot] = src[e];
    }
}

// ---------------------------------------------------------------------------
// Tiled dual linear: outl = xin @ Wl, outr = xin @ Wr + b.
// Block owns TR=64 rows; x-tile staged in LDS (32 KB). Each thread computes
// RPT rows x 4 cols for BOTH matrices -> W L2 traffic amortized RPT x.
// k-loop unrolled by 4 so x comes out of LDS as ds_read_b128.
// ---------------------------------------------------------------------------
template<int K, int M, int TR, int RPT>
__global__ __launch_bounds__((M / 4) * (TR / RPT))
void dual_linear_tiled(const float* __restrict__ xin,
                       const float* __restrict__ Wl, const float* __restrict__ Wr,
                       const float* __restrict__ bias,
                       float* __restrict__ outl, float* __restrict__ outr, int N) {
    constexpr int CG = M / 4;        // col groups (threads per row-set)
    constexpr int RG = TR / RPT;     // row groups
    constexpr int NT = CG * RG;      // threads per block
    __shared__ float xs[TR][K];

    const int tid = threadIdx.x;
    const int tx = tid % CG;         // col group -> cols j..j+3
    const int ty = tid / CG;         // row group -> rows r0..r0+RPT-1
    const long rowBase = (long)blockIdx.x * TR;

    // ---- stage x tile (coalesced float4 loads) ----
    constexpr int TOT4 = TR * K / 4;
    #pragma unroll
    for (int it = 0; it < TOT4 / NT; ++it) {
        int idx = it * NT + tid;
        int r = idx / (K / 4);
        int c = idx % (K / 4);
        long gr = rowBase + r;
        float4 v = make_float4(0.f, 0.f, 0.f, 0.f);
        if (gr < N) v = *(const float4*)(xin + gr * K + c * 4);
        *(float4*)(&xs[r][c * 4]) = v;
    }
    __syncthreads();

    const int j = tx << 2;
    const int r0 = ty * RPT;
    float4 bv = *(const float4*)(bias + j);
    float4 accl[RPT], accr[RPT];
    #pragma unroll
    for (int r = 0; r < RPT; ++r) {
        accl[r] = make_float4(0.f, 0.f, 0.f, 0.f);
        accr[r] = bv;
    }

    for (int k0 = 0; k0 < K; k0 += 4) {
        float4 wl0 = *(const float4*)(Wl + (long)(k0 + 0) * M + j);
        float4 wl1 = *(const float4*)(Wl + (long)(k0 + 1) * M + j);
        float4 wl2 = *(const float4*)(Wl + (long)(k0 + 2) * M + j);
        float4 wl3 = *(const float4*)(Wl + (long)(k0 + 3) * M + j);
        float4 wr0 = *(const float4*)(Wr + (long)(k0 + 0) * M + j);
        float4 wr1 = *(const float4*)(Wr + (long)(k0 + 1) * M + j);
        float4 wr2 = *(const float4*)(Wr + (long)(k0 + 2) * M + j);
        float4 wr3 = *(const float4*)(Wr + (long)(k0 + 3) * M + j);
        #pragma unroll
        for (int r = 0; r < RPT; ++r) {
            float4 xv = *(const float4*)(&xs[r0 + r][k0]);
            #define FMA4(acc, w0, w1, w2, w3)                    \
                acc.x = fmaf(xv.x, w0.x, acc.x);                 \
                acc.y = fmaf(xv.x, w0.y, acc.y);                 \
                acc.z = fmaf(xv.x, w0.z, acc.z);                 \
                acc.w = fmaf(xv.x, w0.w, acc.w);                 \
                acc.x = fmaf(xv.y, w1.x, acc.x);                 \
                acc.y = fmaf(xv.y, w1.y, acc.y);                 \
                acc.z = fmaf(xv.y, w1.z, acc.z);                 \
                acc.w = fmaf(xv.y, w1.w, acc.w);                 \
                acc.x = fmaf(xv.z, w2.x, acc.x);                 \
                acc.y = fmaf(xv.z, w2.y, acc.y);                 \
                acc.z = fmaf(xv.z, w2.z, acc.z);                 \
                acc.w = fmaf(xv.z, w2.w, acc.w);                 \
                acc.x = fmaf(xv.w, w3.x, acc.x);                 \
                acc.y = fmaf(xv.w, w3.y, acc.y);                 \
                acc.z = fmaf(xv.w, w3.z, acc.z);                 \
                acc.w = fmaf(xv.w, w3.w, acc.w);
            FMA4(accl[r], wl0, wl1, wl2, wl3)
            FMA4(accr[r], wr0, wr1, wr2, wr3)
            #undef FMA4
        }
    }

    #pragma unroll
    for (int r = 0; r < RPT; ++r) {
        long i = rowBase + r0 + r;
        if (i < N) {
            *(float4*)(outl + i * M + j) = accl[r];
            *(float4*)(outr + i * M + j) = accr[r];
        }
    }
}

// ---------------------------------------------------------------------------
// Gather aggregation: out[i] = act( mean_{s in nbr(i)} gl[s] + rr[i] )
// Group of M/4 lanes per node, float4 per lane; neighbor loop 4x unrolled
// with two accumulators for MLP.
// ---------------------------------------------------------------------------
template<int M, bool RELU>
__global__ void gather_agg(const float* __restrict__ gl, const float* __restrict__ rr,
                           const int* __restrict__ rp, const int* __restrict__ col,
                           float* __restrict__ out, int N) {
    constexpr int G = M / 4;
    long t = (long)blockIdx.x * blockDim.x + threadIdx.x;
    long i = t / G;
    if (i >= N) return;
    int c = ((int)(t % G)) << 2;

    int beg = rp[i], end = rp[i + 1];
    float4 a0 = make_float4(0.f, 0.f, 0.f, 0.f);
    float4 a1 = make_float4(0.f, 0.f, 0.f, 0.f);
    int e = beg;
    for (; e + 3 < end; e += 4) {
        int s0 = col[e], s1 = col[e + 1], s2 = col[e + 2], s3 = col[e + 3];
        float4 v0 = *(const float4*)(gl + (long)s0 * M + c);
        float4 v1 = *(const float4*)(gl + (long)s1 * M + c);
        float4 v2 = *(const float4*)(gl + (long)s2 * M + c);
        float4 v3 = *(const float4*)(gl + (long)s3 * M + c);
        a0.x += v0.x + v2.x; a0.y += v0.y + v2.y; a0.z += v0.z + v2.z; a0.w += v0.w + v2.w;
        a1.x += v1.x + v3.x; a1.y += v1.y + v3.y; a1.z += v1.z + v3.z; a1.w += v1.w + v3.w;
    }
    for (; e < end; ++e) {
        int s0 = col[e];
        float4 v0 = *(const float4*)(gl + (long)s0 * M + c);
        a0.x += v0.x; a0.y += v0.y; a0.z += v0.z; a0.w += v0.w;
    }
    a0.x += a1.x; a0.y += a1.y; a0.z += a1.z; a0.w += a1.w;

    float inv = 1.0f / fmaxf((float)(end - beg), 1.0f);
    float4 r = *(const float4*)(rr + i * M + c);
    float4 o;
    o.x = fmaf(a0.x, inv, r.x);
    o.y = fmaf(a0.y, inv, r.y);
    o.z = fmaf(a0.z, inv, r.z);
    o.w = fmaf(a0.w, inv, r.w);
    if (RELU) {
        o.x = fmaxf(o.x, 0.f); o.y = fmaxf(o.y, 0.f);
        o.z = fmaxf(o.z, 0.f); o.w = fmaxf(o.w, 0.f);
    }
    *(float4*)(out + i * M + c) = o;
}

extern "C" void kernel_launch(void* const* d_in, const int* in_sizes, int n_in,
                              void* d_out, int out_size, void* d_ws, size_t ws_size,
                              hipStream_t stream) {
    const float* x   = (const float*)d_in[0];   // [N, 128]
    const int*   ei  = (const int*)  d_in[1];   // [2, E]
    const float* W1l = (const float*)d_in[2];   // [128, 128]
    const float* W1r = (const float*)d_in[3];   // [128, 128]
    const float* b1  = (const float*)d_in[4];   // [128]
    const float* W2l = (const float*)d_in[5];   // [128, 64]
    const float* W2r = (const float*)d_in[6];   // [128, 64]
    const float* b2  = (const float*)d_in[7];   // [64]
    float* out = (float*)d_out;                 // [N, 64]

    const int N = in_sizes[0] / D_IN;
    const int E = in_sizes[1] / 2;
    const int* src = ei;        // edge_index[0]
    const int* dst = ei + E;    // edge_index[1]

    // -------- workspace layout --------
    float* bufA = (float*)d_ws;                       // xl ; later hl|hr
    float* bufB = bufA + (size_t)N * D_HID;           // xr -> h (in place)
    int*   rp     = (int*)(bufB + (size_t)N * D_HID);
    int*   cnt    = rp + (N + 1);
    int*   cursor = cnt + N;
    int*   col    = cursor + N;

    // -------- CSR build --------
    hipMemsetAsync(cnt, 0, (size_t)N * sizeof(int), stream);
    hist_kernel<<<(E + 255) / 256, 256, 0, stream>>>(dst, cnt, E);
    scan_kernel<<<1, 1024, 0, stream>>>(cnt, rp, cursor, N);
    fill_kernel<<<(E + 255) / 256, 256, 0, stream>>>(src, dst, cursor, col, E);

    const int TR = 64;
    const int nTiles = (N + TR - 1) / TR;

    // -------- layer 1 --------
    dual_linear_tiled<D_IN, D_HID, 64, 8>
        <<<nTiles, 256, 0, stream>>>(x, W1l, W1r, b1, bufA, bufB, N);
    {
        long T = (long)N * (D_HID / 4);
        gather_agg<D_HID, true>
            <<<(int)((T + 255) / 256), 256, 0, stream>>>(bufA, bufB, rp, col, bufB, N);
    }

    // -------- layer 2 --------
    float* hl = bufA;                      // [N, 64]
    float* hr = bufA + (size_t)N * D_OUT;  // [N, 64]
    dual_linear_tiled<D_HID, D_OUT, 64, 4>
        <<<nTiles, 256, 0, stream>>>(bufB, W2l, W2r, b2, hl, hr, N);
    {
        long T = (long)N * (D_OUT / 4);
        gather_agg<D_OUT, false>
            <<<(int)((T + 255) / 256), 256, 0, stream>>>(hl, hr, rp, col, out, N);
    }
}

// Round 6
// 290.100 us; speedup vs baseline: 10.6883x; 1.3053x over previous
//
#include <hip/hip_runtime.h>

#define D_IN  128
#define D_HID 128
#define D_OUT 64

// ---------------------------------------------------------------------------
// CSR build step 1: cnt[n] = in-degree of node n
// ---------------------------------------------------------------------------
__global__ void hist_kernel(const int* __restrict__ dst, int* __restrict__ cnt, int E) {
    int e = blockIdx.x * blockDim.x + threadIdx.x;
    if (e < E) atomicAdd(&cnt[dst[e]], 1);
}

// ---------------------------------------------------------------------------
// CSR build step 2 (replaces the 110us single-block scan): allocate each
// node's segment with a wave-level prefix scan + one atomicAdd per wave.
// Segment PLACEMENT need not be in node order -- gather uses beg[i]/cnt[i].
// ---------------------------------------------------------------------------
__global__ void seg_assign(const int* __restrict__ cnt, int* __restrict__ beg,
                           int* __restrict__ cursor, int* __restrict__ total, int N) {
    int i = blockIdx.x * blockDim.x + threadIdx.x;
    int lane = threadIdx.x & 63;
    int c = (i < N) ? cnt[i] : 0;
    int pref = c;                       // inclusive prefix within wave
    #pragma unroll
    for (int off = 1; off < 64; off <<= 1) {
        int v = __shfl_up(pref, off, 64);
        if (lane >= off) pref += v;
    }
    int waveTot = __shfl(pref, 63, 64);
    int base = 0;
    if (lane == 63) base = atomicAdd(total, waveTot);
    base = __shfl(base, 63, 64);
    if (i < N) {
        int b = base + pref - c;        // exclusive within wave + global base
        beg[i] = b;
        cursor[i] = b;
    }
}

// ---------------------------------------------------------------------------
// CSR build step 3: col[slot] = src[e], slot handed out by per-dst cursor.
// ---------------------------------------------------------------------------
__global__ void fill_kernel(const int* __restrict__ src, const int* __restrict__ dst,
                            int* __restrict__ cursor, int* __restrict__ col, int E) {
    int e = blockIdx.x * blockDim.x + threadIdx.x;
    if (e < E) {
        int slot = atomicAdd(&cursor[dst[e]], 1);
        col[slot] = src[e];
    }
}

// ---------------------------------------------------------------------------
// Tiled dual linear: outl = xin @ Wl, outr = xin @ Wr + b.
// Block owns TR=64 rows; x-tile staged in LDS (32 KB). Each thread computes
// RPT rows x 4 cols for BOTH matrices -> W L2 traffic amortized RPT x.
// ---------------------------------------------------------------------------
template<int K, int M, int TR, int RPT>
__global__ __launch_bounds__((M / 4) * (TR / RPT))
void dual_linear_tiled(const float* __restrict__ xin,
                       const float* __restrict__ Wl, const float* __restrict__ Wr,
                       const float* __restrict__ bias,
                       float* __restrict__ outl, float* __restrict__ outr, int N) {
    constexpr int CG = M / 4;        // col groups
    constexpr int RG = TR / RPT;     // row groups
    constexpr int NT = CG * RG;      // threads per block
    __shared__ float xs[TR][K];

    const int tid = threadIdx.x;
    const int tx = tid % CG;
    const int ty = tid / CG;
    const long rowBase = (long)blockIdx.x * TR;

    constexpr int TOT4 = TR * K / 4;
    #pragma unroll
    for (int it = 0; it < TOT4 / NT; ++it) {
        int idx = it * NT + tid;
        int r = idx / (K / 4);
        int c = idx % (K / 4);
        long gr = rowBase + r;
        float4 v = make_float4(0.f, 0.f, 0.f, 0.f);
        if (gr < N) v = *(const float4*)(xin + gr * K + c * 4);
        *(float4*)(&xs[r][c * 4]) = v;
    }
    __syncthreads();

    const int j = tx << 2;
    const int r0 = ty * RPT;
    float4 bv = *(const float4*)(bias + j);
    float4 accl[RPT], accr[RPT];
    #pragma unroll
    for (int r = 0; r < RPT; ++r) {
        accl[r] = make_float4(0.f, 0.f, 0.f, 0.f);
        accr[r] = bv;
    }

    for (int k0 = 0; k0 < K; k0 += 4) {
        float4 wl0 = *(const float4*)(Wl + (long)(k0 + 0) * M + j);
        float4 wl1 = *(const float4*)(Wl + (long)(k0 + 1) * M + j);
        float4 wl2 = *(const float4*)(Wl + (long)(k0 + 2) * M + j);
        float4 wl3 = *(const float4*)(Wl + (long)(k0 + 3) * M + j);
        float4 wr0 = *(const float4*)(Wr + (long)(k0 + 0) * M + j);
        float4 wr1 = *(const float4*)(Wr + (long)(k0 + 1) * M + j);
        float4 wr2 = *(const float4*)(Wr + (long)(k0 + 2) * M + j);
        float4 wr3 = *(const float4*)(Wr + (long)(k0 + 3) * M + j);
        #pragma unroll
        for (int r = 0; r < RPT; ++r) {
            float4 xv = *(const float4*)(&xs[r0 + r][k0]);
            #define FMA4(acc, w0, w1, w2, w3)                    \
                acc.x = fmaf(xv.x, w0.x, acc.x);                 \
                acc.y = fmaf(xv.x, w0.y, acc.y);                 \
                acc.z = fmaf(xv.x, w0.z, acc.z);                 \
                acc.w = fmaf(xv.x, w0.w, acc.w);                 \
                acc.x = fmaf(xv.y, w1.x, acc.x);                 \
                acc.y = fmaf(xv.y, w1.y, acc.y);                 \
                acc.z = fmaf(xv.y, w1.z, acc.z);                 \
                acc.w = fmaf(xv.y, w1.w, acc.w);                 \
                acc.x = fmaf(xv.z, w2.x, acc.x);                 \
                acc.y = fmaf(xv.z, w2.y, acc.y);                 \
                acc.z = fmaf(xv.z, w2.z, acc.z);                 \
                acc.w = fmaf(xv.z, w2.w, acc.w);                 \
                acc.x = fmaf(xv.w, w3.x, acc.x);                 \
                acc.y = fmaf(xv.w, w3.y, acc.y);                 \
                acc.z = fmaf(xv.w, w3.z, acc.z);                 \
                acc.w = fmaf(xv.w, w3.w, acc.w);
            FMA4(accl[r], wl0, wl1, wl2, wl3)
            FMA4(accr[r], wr0, wr1, wr2, wr3)
            #undef FMA4
        }
    }

    #pragma unroll
    for (int r = 0; r < RPT; ++r) {
        long i = rowBase + r0 + r;
        if (i < N) {
            *(float4*)(outl + i * M + j) = accl[r];
            *(float4*)(outr + i * M + j) = accr[r];
        }
    }
}

// ---------------------------------------------------------------------------
// Gather aggregation: out[i] = act( mean_{s in nbr(i)} gl[s] + rr[i] )
// Segment of node i lives at col[beg[i] .. beg[i]+cnt[i]).
// ---------------------------------------------------------------------------
template<int M, bool RELU>
__global__ void gather_agg(const float* __restrict__ gl, const float* __restrict__ rr,
                           const int* __restrict__ beg, const int* __restrict__ cnt,
                           const int* __restrict__ col,
                           float* __restrict__ out, int N) {
    constexpr int G = M / 4;
    long t = (long)blockIdx.x * blockDim.x + threadIdx.x;
    long i = t / G;
    if (i >= N) return;
    int c = ((int)(t % G)) << 2;

    int b0 = beg[i];
    int deg = cnt[i];
    int end = b0 + deg;
    float4 a0 = make_float4(0.f, 0.f, 0.f, 0.f);
    float4 a1 = make_float4(0.f, 0.f, 0.f, 0.f);
    int e = b0;
    for (; e + 3 < end; e += 4) {
        int s0 = col[e], s1 = col[e + 1], s2 = col[e + 2], s3 = col[e + 3];
        float4 v0 = *(const float4*)(gl + (long)s0 * M + c);
        float4 v1 = *(const float4*)(gl + (long)s1 * M + c);
        float4 v2 = *(const float4*)(gl + (long)s2 * M + c);
        float4 v3 = *(const float4*)(gl + (long)s3 * M + c);
        a0.x += v0.x + v2.x; a0.y += v0.y + v2.y; a0.z += v0.z + v2.z; a0.w += v0.w + v2.w;
        a1.x += v1.x + v3.x; a1.y += v1.y + v3.y; a1.z += v1.z + v3.z; a1.w += v1.w + v3.w;
    }
    for (; e < end; ++e) {
        int s0 = col[e];
        float4 v0 = *(const float4*)(gl + (long)s0 * M + c);
        a0.x += v0.x; a0.y += v0.y; a0.z += v0.z; a0.w += v0.w;
    }
    a0.x += a1.x; a0.y += a1.y; a0.z += a1.z; a0.w += a1.w;

    float inv = 1.0f / fmaxf((float)deg, 1.0f);
    float4 r = *(const float4*)(rr + i * M + c);
    float4 o;
    o.x = fmaf(a0.x, inv, r.x);
    o.y = fmaf(a0.y, inv, r.y);
    o.z = fmaf(a0.z, inv, r.z);
    o.w = fmaf(a0.w, inv, r.w);
    if (RELU) {
        o.x = fmaxf(o.x, 0.f); o.y = fmaxf(o.y, 0.f);
        o.z = fmaxf(o.z, 0.f); o.w = fmaxf(o.w, 0.f);
    }
    *(float4*)(out + i * M + c) = o;
}

extern "C" void kernel_launch(void* const* d_in, const int* in_sizes, int n_in,
                              void* d_out, int out_size, void* d_ws, size_t ws_size,
                              hipStream_t stream) {
    const float* x   = (const float*)d_in[0];   // [N, 128]
    const int*   ei  = (const int*)  d_in[1];   // [2, E]
    const float* W1l = (const float*)d_in[2];   // [128, 128]
    const float* W1r = (const float*)d_in[3];   // [128, 128]
    const float* b1  = (const float*)d_in[4];   // [128]
    const float* W2l = (const float*)d_in[5];   // [128, 64]
    const float* W2r = (const float*)d_in[6];   // [128, 64]
    const float* b2  = (const float*)d_in[7];   // [64]
    float* out = (float*)d_out;                 // [N, 64]

    const int N = in_sizes[0] / D_IN;
    const int E = in_sizes[1] / 2;
    const int* src = ei;        // edge_index[0]
    const int* dst = ei + E;    // edge_index[1]

    // -------- workspace layout --------
    // bufA [N*128] f32 : xl ; later hl|hr
    // bufB [N*128] f32 : xr -> h (in place)
    // ints: cnt[N] | total[1]  (zeroed together) | beg[N] | cursor[N] | col[E]
    float* bufA = (float*)d_ws;
    float* bufB = bufA + (size_t)N * D_HID;
    int*   cnt    = (int*)(bufB + (size_t)N * D_HID);
    int*   total  = cnt + N;
    int*   beg    = total + 1;
    int*   cursor = beg + N;
    int*   col    = cursor + N;

    // -------- CSR build --------
    hipMemsetAsync(cnt, 0, (size_t)(N + 1) * sizeof(int), stream);   // cnt + total
    hist_kernel<<<(E + 255) / 256, 256, 0, stream>>>(dst, cnt, E);
    seg_assign<<<(N + 255) / 256, 256, 0, stream>>>(cnt, beg, cursor, total, N);
    fill_kernel<<<(E + 255) / 256, 256, 0, stream>>>(src, dst, cursor, col, E);

    const int TR = 64;
    const int nTiles = (N + TR - 1) / TR;

    // -------- layer 1 --------
    dual_linear_tiled<D_IN, D_HID, 64, 8>
        <<<nTiles, 256, 0, stream>>>(x, W1l, W1r, b1, bufA, bufB, N);
    {
        long T = (long)N * (D_HID / 4);
        gather_agg<D_HID, true>
            <<<(int)((T + 255) / 256), 256, 0, stream>>>(bufA, bufB, beg, cnt, col, bufB, N);
    }

    // -------- layer 2 --------
    float* hl = bufA;                      // [N, 64]
    float* hr = bufA + (size_t)N * D_OUT;  // [N, 64]
    dual_linear_tiled<D_HID, D_OUT, 64, 4>
        <<<nTiles, 256, 0, stream>>>(bufB, W2l, W2r, b2, hl, hr, N);
    {
        long T = (long)N * (D_OUT / 4);
        gather_agg<D_OUT, false>
            <<<(int)((T + 255) / 256), 256, 0, stream>>>(hl, hr, beg, cnt, col, out, N);
    }
}

// Round 7
// 224.753 us; speedup vs baseline: 13.7960x; 1.2908x over previous
//
#include <hip/hip_runtime.h>

#define D_IN  128
#define D_HID 128
#define D_OUT 64

typedef __attribute__((ext_vector_type(8))) short bf16x8;
typedef __attribute__((ext_vector_type(4))) float f32x4;

__device__ __forceinline__ short f2bf(float f) {
    union { float f; unsigned u; } cv; cv.f = f;
    unsigned r = (cv.u + 0x7FFFu + ((cv.u >> 16) & 1u)) >> 16;
    return (short)r;
}
__device__ __forceinline__ float bf2f(short s) {
    union { unsigned u; float f; } cv;
    cv.u = ((unsigned)(unsigned short)s) << 16;
    return cv.f;
}

// ---------------------------------------------------------------------------
// f32 -> bf16 bulk convert (grid-stride, float4 in / short4 out)
// ---------------------------------------------------------------------------
__global__ void conv_bf16(const float* __restrict__ in, short* __restrict__ out, long n4) {
    long stride = (long)gridDim.x * blockDim.x;
    for (long t = (long)blockIdx.x * blockDim.x + threadIdx.x; t < n4; t += stride) {
        float4 v = ((const float4*)in)[t];
        short4 o = { f2bf(v.x), f2bf(v.y), f2bf(v.z), f2bf(v.w) };
        ((short4*)out)[t] = o;
    }
}

// ---------------------------------------------------------------------------
// Build transposed bf16 weight: Wt[c][k] = (c<CL ? Wl[k][c] : Wr[k][c-CL])
// Wl is [128][CL], Wr is [128][CR], Wt is [(CL+CR)][128].
// ---------------------------------------------------------------------------
__global__ void build_wt(const float* __restrict__ Wl, const float* __restrict__ Wr,
                         short* __restrict__ Wt, int CL, int CR) {
    int idx = blockIdx.x * blockDim.x + threadIdx.x;
    int total = (CL + CR) * 128;
    if (idx >= total) return;
    int c = idx >> 7;
    int k = idx & 127;
    float v = (c < CL) ? Wl[k * CL + c] : Wr[k * CR + (c - CL)];
    Wt[idx] = f2bf(v);
}

// ---------------------------------------------------------------------------
// CSR build: histogram, segment assignment (wave scan + atomic base), fill.
// ---------------------------------------------------------------------------
__global__ void hist_kernel(const int* __restrict__ dst, int* __restrict__ cnt, int E) {
    int e = blockIdx.x * blockDim.x + threadIdx.x;
    if (e < E) atomicAdd(&cnt[dst[e]], 1);
}

__global__ void seg_assign(const int* __restrict__ cnt, int* __restrict__ beg,
                           int* __restrict__ cursor, int* __restrict__ total, int N) {
    int i = blockIdx.x * blockDim.x + threadIdx.x;
    int lane = threadIdx.x & 63;
    int c = (i < N) ? cnt[i] : 0;
    int pref = c;
    #pragma unroll
    for (int off = 1; off < 64; off <<= 1) {
        int v = __shfl_up(pref, off, 64);
        if (lane >= off) pref += v;
    }
    int waveTot = __shfl(pref, 63, 64);
    int base = 0;
    if (lane == 63) base = atomicAdd(total, waveTot);
    base = __shfl(base, 63, 64);
    if (i < N) {
        int b = base + pref - c;
        beg[i] = b;
        cursor[i] = b;
    }
}

__global__ void fill_kernel(const int* __restrict__ src, const int* __restrict__ dst,
                            int* __restrict__ cursor, int* __restrict__ col, int E) {
    int e = blockIdx.x * blockDim.x + threadIdx.x;
    if (e < E) {
        int slot = atomicAdd(&cursor[dst[e]], 1);
        col[slot] = src[e];
    }
}

// ---------------------------------------------------------------------------
// MFMA dual GEMM: [outL | outR] = A @ Wt^T, outR += bias.
// A [N][128] bf16, Wt [NCOLS][128] bf16 (B^T layout), f32 accumulate.
// Block = 4 waves; each wave owns a 64x64 output tile (4x4 frags of 16x16).
// Fragments are loaded straight from global (L1/L2-resident, no LDS).
// 16x16x32 layouts: A: row=lane&15, k=(lane>>4)*8+j (contiguous 16B);
// B^T row: col=lane&15, same k; C/D: col=lane&15, row=(lane>>4)*4+reg.
// ---------------------------------------------------------------------------
template<int NCOLS, int LEFT>
__global__ __launch_bounds__(256)
void gemm_dual(const short* __restrict__ A, const short* __restrict__ Wt,
               const float* __restrict__ bias,
               short* __restrict__ outL, float* __restrict__ outR, int N) {
    constexpr int K = 128;
    constexpr int WC = NCOLS / 64;      // waves along cols
    constexpr int WR = 4 / WC;          // waves along rows
    constexpr int BM = WR * 64;         // rows per block
    constexpr int RIGHT = NCOLS - LEFT;

    const int wid  = threadIdx.x >> 6;
    const int lane = threadIdx.x & 63;
    const int wc = wid % WC, wr = wid / WC;
    const long rowBase = (long)blockIdx.x * BM + (long)wr * 64;
    const int colBase = wc * 64;
    const int l15 = lane & 15;
    const int kq  = lane >> 4;          // 0..3

    f32x4 acc[4][4] = {};

    #pragma unroll
    for (int s = 0; s < 4; ++s) {       // K-steps of 32
        const int ko = s * 32 + kq * 8;
        bf16x8 a[4], b[4];
        #pragma unroll
        for (int r = 0; r < 4; ++r) {
            long row = rowBase + r * 16 + l15;
            row = row < N ? row : (long)N - 1;          // clamp; store guarded
            a[r] = *(const bf16x8*)(A + row * K + ko);
        }
        #pragma unroll
        for (int f = 0; f < 4; ++f) {
            long c = colBase + f * 16 + l15;
            b[f] = *(const bf16x8*)(Wt + c * K + ko);
        }
        #pragma unroll
        for (int r = 0; r < 4; ++r)
            #pragma unroll
            for (int f = 0; f < 4; ++f)
                acc[r][f] = __builtin_amdgcn_mfma_f32_16x16x32_bf16(a[r], b[f], acc[r][f], 0, 0, 0);
    }

    // epilogue: col<LEFT -> bf16 outL ; else f32 outR + bias (wave-uniform split)
    #pragma unroll
    for (int r = 0; r < 4; ++r) {
        #pragma unroll
        for (int f = 0; f < 4; ++f) {
            int col = colBase + f * 16 + l15;
            #pragma unroll
            for (int j = 0; j < 4; ++j) {
                long row = rowBase + r * 16 + kq * 4 + j;
                if (row < N) {
                    float v = acc[r][f][j];
                    if (col < LEFT) {
                        outL[row * LEFT + col] = f2bf(v);
                    } else {
                        outR[row * RIGHT + (col - LEFT)] = v + bias[col - LEFT];
                    }
                }
            }
        }
    }
}

// ---------------------------------------------------------------------------
// Gather aggregation: out[i] = act( mean_{s in nbr(i)} gl[s] + rr[i] )
// gl is bf16 [N][M] (halved gather traffic); rr f32 [N][M];
// out bf16 (layer1 h, feeds GEMM2) or f32 (final output).
// ---------------------------------------------------------------------------
template<int M, bool RELU, bool OUTBF16>
__global__ void gather_agg(const short* __restrict__ gl, const float* __restrict__ rr,
                           const int* __restrict__ beg, const int* __restrict__ cnt,
                           const int* __restrict__ col, void* __restrict__ outp, int N) {
    constexpr int G = M / 4;
    long t = (long)blockIdx.x * blockDim.x + threadIdx.x;
    long i = t / G;
    if (i >= N) return;
    int c = ((int)(t % G)) << 2;

    int b0 = beg[i];
    int deg = cnt[i];
    int end = b0 + deg;
    float ax = 0.f, ay = 0.f, az = 0.f, aw = 0.f;
    int e = b0;
    for (; e + 3 < end; e += 4) {
        int s0 = col[e], s1 = col[e + 1], s2 = col[e + 2], s3 = col[e + 3];
        short4 v0 = *(const short4*)(gl + (long)s0 * M + c);
        short4 v1 = *(const short4*)(gl + (long)s1 * M + c);
        short4 v2 = *(const short4*)(gl + (long)s2 * M + c);
        short4 v3 = *(const short4*)(gl + (long)s3 * M + c);
        ax += bf2f(v0.x) + bf2f(v1.x) + bf2f(v2.x) + bf2f(v3.x);
        ay += bf2f(v0.y) + bf2f(v1.y) + bf2f(v2.y) + bf2f(v3.y);
        az += bf2f(v0.z) + bf2f(v1.z) + bf2f(v2.z) + bf2f(v3.z);
        aw += bf2f(v0.w) + bf2f(v1.w) + bf2f(v2.w) + bf2f(v3.w);
    }
    for (; e < end; ++e) {
        short4 v0 = *(const short4*)(gl + (long)col[e] * M + c);
        ax += bf2f(v0.x); ay += bf2f(v0.y); az += bf2f(v0.z); aw += bf2f(v0.w);
    }

    float inv = 1.0f / fmaxf((float)deg, 1.0f);
    float4 r = *(const float4*)(rr + i * M + c);
    float ox = fmaf(ax, inv, r.x);
    float oy = fmaf(ay, inv, r.y);
    float oz = fmaf(az, inv, r.z);
    float ow = fmaf(aw, inv, r.w);
    if (RELU) {
        ox = fmaxf(ox, 0.f); oy = fmaxf(oy, 0.f);
        oz = fmaxf(oz, 0.f); ow = fmaxf(ow, 0.f);
    }
    if (OUTBF16) {
        short4 o = { f2bf(ox), f2bf(oy), f2bf(oz), f2bf(ow) };
        *(short4*)((short*)outp + i * M + c) = o;
    } else {
        float4 o = { ox, oy, oz, ow };
        *(float4*)((float*)outp + i * M + c) = o;
    }
}

extern "C" void kernel_launch(void* const* d_in, const int* in_sizes, int n_in,
                              void* d_out, int out_size, void* d_ws, size_t ws_size,
                              hipStream_t stream) {
    const float* x   = (const float*)d_in[0];   // [N, 128]
    const int*   ei  = (const int*)  d_in[1];   // [2, E]
    const float* W1l = (const float*)d_in[2];   // [128, 128]
    const float* W1r = (const float*)d_in[3];   // [128, 128]
    const float* b1  = (const float*)d_in[4];   // [128]
    const float* W2l = (const float*)d_in[5];   // [128, 64]
    const float* W2r = (const float*)d_in[6];   // [128, 64]
    const float* b2  = (const float*)d_in[7];   // [64]
    float* out = (float*)d_out;                 // [N, 64]

    const int N = in_sizes[0] / D_IN;
    const int E = in_sizes[1] / 2;
    const int* src = ei;
    const int* dst = ei + E;

    // -------- workspace layout (~55 MB, same footprint as last round) --------
    // xb  [N*128] bf16  -> reused as hb  [N*128] bf16
    // xlb [N*128] bf16  -> reused as hlb [N*64]  bf16
    // xr  [N*128] f32   -> reused as hr  [N*64]  f32
    // wt1 [256*128] bf16 | wt2 [128*128] bf16
    // cnt[N] | total[1] | beg[N] | cursor[N] | col[E]
    short* xb  = (short*)d_ws;
    short* xlb = xb + (size_t)N * 128;
    float* xr  = (float*)(xlb + (size_t)N * 128);
    short* wt1 = (short*)(xr + (size_t)N * 128);
    short* wt2 = wt1 + 256 * 128;
    int* cnt    = (int*)(wt2 + 128 * 128);
    int* total  = cnt + N;
    int* beg    = total + 1;
    int* cursor = beg + N;
    int* colArr = cursor + N;

    short* hb  = xb;    // [N,128] bf16 (after gemm1 consumed xb)
    short* hlb = xlb;   // [N,64]  bf16 (after gather1 consumed xlb)
    float* hr  = xr;    // [N,64]  f32  (after gather1 consumed xr)

    // -------- conversions + CSR build --------
    conv_bf16<<<2048, 256, 0, stream>>>(x, xb, (long)N * 128 / 4);
    build_wt<<<(256 * 128 + 255) / 256, 256, 0, stream>>>(W1l, W1r, wt1, 128, 128);
    build_wt<<<(128 * 128 + 255) / 256, 256, 0, stream>>>(W2l, W2r, wt2, 64, 64);
    hipMemsetAsync(cnt, 0, (size_t)(N + 1) * sizeof(int), stream);   // cnt + total
    hist_kernel<<<(E + 255) / 256, 256, 0, stream>>>(dst, cnt, E);
    seg_assign<<<(N + 255) / 256, 256, 0, stream>>>(cnt, beg, cursor, total, N);
    fill_kernel<<<(E + 255) / 256, 256, 0, stream>>>(src, dst, cursor, colArr, E);

    // -------- layer 1: [xl | xr] = x @ [W1l | W1r], xr += b1 --------
    gemm_dual<256, 128><<<(N + 63) / 64, 256, 0, stream>>>(xb, wt1, b1, xlb, xr, N);
    {   // h = relu(mean_gather(xl) + xr), written as bf16
        long T = (long)N * (D_HID / 4);
        gather_agg<D_HID, true, true>
            <<<(int)((T + 255) / 256), 256, 0, stream>>>(xlb, xr, beg, cnt, colArr, hb, N);
    }

    // -------- layer 2: [hl | hr] = h @ [W2l | W2r], hr += b2 --------
    gemm_dual<128, 64><<<(N + 127) / 128, 256, 0, stream>>>(hb, wt2, b2, hlb, hr, N);
    {   // out = mean_gather(hl) + hr  (f32 to d_out)
        long T = (long)N * (D_OUT / 4);
        gather_agg<D_OUT, false, false>
            <<<(int)((T + 255) / 256), 256, 0, stream>>>(hlb, hr, beg, cnt, colArr, out, N);
    }
}

// Round 8
// 169.392 us; speedup vs baseline: 18.3048x; 1.3268x over previous
//
#include <hip/hip_runtime.h>

#define D_IN  128
#define D_HID 128
#define D_OUT 64
#define NPB   256        // nodes per bucket (dst >> 8); requires N <= 65536
#define CH    8192       // edges per bucket_fill block-chunk

typedef __attribute__((ext_vector_type(8))) short bf16x8;
typedef __attribute__((ext_vector_type(4))) float f32x4;

__device__ __forceinline__ short f2bf(float f) {
    union { float f; unsigned u; } cv; cv.f = f;
    unsigned r = (cv.u + 0x7FFFu + ((cv.u >> 16) & 1u)) >> 16;
    return (short)r;
}
__device__ __forceinline__ float bf2f(short s) {
    union { unsigned u; float f; } cv;
    cv.u = ((unsigned)(unsigned short)s) << 16;
    return cv.f;
}

// ---------------------------------------------------------------------------
// f32 -> bf16 bulk convert
// ---------------------------------------------------------------------------
__global__ void conv_bf16(const float* __restrict__ in, short* __restrict__ out, long n4) {
    long stride = (long)gridDim.x * blockDim.x;
    for (long t = (long)blockIdx.x * blockDim.x + threadIdx.x; t < n4; t += stride) {
        float4 v = ((const float4*)in)[t];
        short4 o = { f2bf(v.x), f2bf(v.y), f2bf(v.z), f2bf(v.w) };
        ((short4*)out)[t] = o;
    }
}

// ---------------------------------------------------------------------------
// Wt[c][k] = (c<CL ? Wl[k][c] : Wr[k][c-CL]), bf16, B^T layout for MFMA
// ---------------------------------------------------------------------------
__global__ void build_wt(const float* __restrict__ Wl, const float* __restrict__ Wr,
                         short* __restrict__ Wt, int CL, int CR) {
    int idx = blockIdx.x * blockDim.x + threadIdx.x;
    int total = (CL + CR) * 128;
    if (idx >= total) return;
    int c = idx >> 7;
    int k = idx & 127;
    float v = (c < CL) ? Wl[k * CL + c] : Wr[k * CR + (c - CL)];
    Wt[idx] = f2bf(v);
}

// ---------------------------------------------------------------------------
// CSR build, two-level counting sort (no cross-XCD partial-line scatter).
// Level 1: bucket = dst >> 8 (NPB=256 nodes/bucket, NB <= 256 buckets).
// ---------------------------------------------------------------------------
__global__ void bucket_hist(const int* __restrict__ dst, int* __restrict__ gh,
                            int E, int NB) {
    __shared__ int lh[256];
    lh[threadIdx.x] = 0;
    __syncthreads();
    long stride = (long)gridDim.x * blockDim.x;
    for (long e = (long)blockIdx.x * blockDim.x + threadIdx.x; e < E; e += stride)
        atomicAdd(&lh[dst[e] >> 8], 1);
    __syncthreads();
    int t = threadIdx.x;
    if (t < NB && lh[t]) atomicAdd(&gh[t], lh[t]);
}

__global__ void bucket_scan(const int* __restrict__ gh, int* __restrict__ pbase,
                            int* __restrict__ pcur, int E, int NB) {
    __shared__ int s[256];
    int t = threadIdx.x;
    int v = (t < NB) ? gh[t] : 0;
    s[t] = v;
    __syncthreads();
    for (int off = 1; off < 256; off <<= 1) {
        int u = (t >= off) ? s[t - off] : 0;
        __syncthreads();
        s[t] += u;
        __syncthreads();
    }
    int excl = s[t] - v;
    if (t < NB) { pbase[t] = excl; pcur[t] = excl; }
    if (t == 0) pbase[NB] = E;
}

// Each block: LDS-histogram its CH-edge chunk per bucket, reserve a contiguous
// window per bucket with ONE global atomic, then write packed records
// (dstLocal<<16 | src) into that window -> writes are line-clustered per block.
__global__ void bucket_fill(const int* __restrict__ src, const int* __restrict__ dst,
                            int* __restrict__ pcur, int* __restrict__ pairs,
                            int E, int NB) {
    __shared__ int lh[256];
    __shared__ int lbase[256];
    __shared__ int lcur[256];
    const int t = threadIdx.x;
    for (long cbase = (long)blockIdx.x * CH; cbase < E; cbase += (long)gridDim.x * CH) {
        int lo = (int)cbase;
        int hi = min(E, lo + CH);
        lh[t] = 0;
        __syncthreads();
        for (int e = lo + t; e < hi; e += 256)
            atomicAdd(&lh[dst[e] >> 8], 1);
        __syncthreads();
        int c = lh[t];
        lbase[t] = (t < NB && c) ? atomicAdd(&pcur[t], c) : 0;
        lcur[t] = 0;
        __syncthreads();
        for (int e = lo + t; e < hi; e += 256) {
            int d = dst[e];
            int b = d >> 8;
            int off = atomicAdd(&lcur[b], 1);
            pairs[lbase[b] + off] = ((d & (NPB - 1)) << 16) | src[e];
        }
        __syncthreads();
    }
}

// One block per bucket: per-node LDS histogram + scan -> cnt/beg, then reorder
// the bucket's pair region into the final col segment (block-private writes).
__global__ void node_fill(const int* __restrict__ pairs, const int* __restrict__ pbase,
                          int* __restrict__ cnt, int* __restrict__ beg,
                          int* __restrict__ col, int N) {
    __shared__ int h[256];
    __shared__ int s[256];
    const int t = threadIdx.x;
    const int b = blockIdx.x;
    const int lo = b << 8;
    const int p0 = pbase[b], p1 = pbase[b + 1];

    h[t] = 0;
    __syncthreads();
    for (int p = p0 + t; p < p1; p += 256)
        atomicAdd(&h[pairs[p] >> 16], 1);
    __syncthreads();
    int v = h[t];
    s[t] = v;
    __syncthreads();
    for (int off = 1; off < 256; off <<= 1) {
        int u = (t >= off) ? s[t - off] : 0;
        __syncthreads();
        s[t] += u;
        __syncthreads();
    }
    int excl = s[t] - v;
    __syncthreads();
    s[t] = p0 + excl;          // segment base for local node t
    h[t] = 0;                  // reuse as per-node cursor
    int i = lo + t;
    if (i < N) { cnt[i] = v; beg[i] = p0 + excl; }
    __syncthreads();
    for (int p = p0 + t; p < p1; p += 256) {
        int pr = pairs[p];
        int nl = pr >> 16;
        int off = atomicAdd(&h[nl], 1);
        col[s[nl] + off] = pr & 0xFFFF;
    }
}

// ---------------------------------------------------------------------------
// MFMA dual GEMM: [outL | outR] = A @ Wt^T, outR += bias. (unchanged)
// ---------------------------------------------------------------------------
template<int NCOLS, int LEFT>
__global__ __launch_bounds__(256)
void gemm_dual(const short* __restrict__ A, const short* __restrict__ Wt,
               const float* __restrict__ bias,
               short* __restrict__ outL, float* __restrict__ outR, int N) {
    constexpr int K = 128;
    constexpr int WC = NCOLS / 64;
    constexpr int WR = 4 / WC;
    constexpr int BM = WR * 64;
    constexpr int RIGHT = NCOLS - LEFT;

    const int wid  = threadIdx.x >> 6;
    const int lane = threadIdx.x & 63;
    const int wc = wid % WC, wr = wid / WC;
    const long rowBase = (long)blockIdx.x * BM + (long)wr * 64;
    const int colBase = wc * 64;
    const int l15 = lane & 15;
    const int kq  = lane >> 4;

    f32x4 acc[4][4] = {};

    #pragma unroll
    for (int s = 0; s < 4; ++s) {
        const int ko = s * 32 + kq * 8;
        bf16x8 a[4], bfr[4];
        #pragma unroll
        for (int r = 0; r < 4; ++r) {
            long row = rowBase + r * 16 + l15;
            row = row < N ? row : (long)N - 1;
            a[r] = *(const bf16x8*)(A + row * K + ko);
        }
        #pragma unroll
        for (int f = 0; f < 4; ++f) {
            long c = colBase + f * 16 + l15;
            bfr[f] = *(const bf16x8*)(Wt + c * K + ko);
        }
        #pragma unroll
        for (int r = 0; r < 4; ++r)
            #pragma unroll
            for (int f = 0; f < 4; ++f)
                acc[r][f] = __builtin_amdgcn_mfma_f32_16x16x32_bf16(a[r], bfr[f], acc[r][f], 0, 0, 0);
    }

    #pragma unroll
    for (int r = 0; r < 4; ++r) {
        #pragma unroll
        for (int f = 0; f < 4; ++f) {
            int col = colBase + f * 16 + l15;
            #pragma unroll
            for (int j = 0; j < 4; ++j) {
                long row = rowBase + r * 16 + kq * 4 + j;
                if (row < N) {
                    float v = acc[r][f][j];
                    if (col < LEFT) {
                        outL[row * LEFT + col] = f2bf(v);
                    } else {
                        outR[row * RIGHT + (col - LEFT)] = v + bias[col - LEFT];
                    }
                }
            }
        }
    }
}

// ---------------------------------------------------------------------------
// Gather aggregation: out[i] = act( mean_{s in nbr(i)} gl[s] + rr[i] )
// bf16x8 loads: 16B/lane, M/8 lanes per node.
// ---------------------------------------------------------------------------
template<int M, bool RELU, bool OUTBF16>
__global__ void gather_agg(const short* __restrict__ gl, const float* __restrict__ rr,
                           const int* __restrict__ beg, const int* __restrict__ cnt,
                           const int* __restrict__ col, void* __restrict__ outp, int N) {
    constexpr int G = M / 8;
    long t = (long)blockIdx.x * blockDim.x + threadIdx.x;
    long i = t / G;
    if (i >= N) return;
    int c = ((int)(t % G)) << 3;

    int b0 = beg[i];
    int deg = cnt[i];
    int end = b0 + deg;
    float a[8] = {0.f, 0.f, 0.f, 0.f, 0.f, 0.f, 0.f, 0.f};
    int e = b0;
    for (; e + 3 < end; e += 4) {
        int s0 = col[e], s1 = col[e + 1], s2 = col[e + 2], s3 = col[e + 3];
        bf16x8 v0 = *(const bf16x8*)(gl + (long)s0 * M + c);
        bf16x8 v1 = *(const bf16x8*)(gl + (long)s1 * M + c);
        bf16x8 v2 = *(const bf16x8*)(gl + (long)s2 * M + c);
        bf16x8 v3 = *(const bf16x8*)(gl + (long)s3 * M + c);
        #pragma unroll
        for (int q = 0; q < 8; ++q)
            a[q] += (bf2f(v0[q]) + bf2f(v1[q])) + (bf2f(v2[q]) + bf2f(v3[q]));
    }
    for (; e < end; ++e) {
        bf16x8 v0 = *(const bf16x8*)(gl + (long)col[e] * M + c);
        #pragma unroll
        for (int q = 0; q < 8; ++q) a[q] += bf2f(v0[q]);
    }

    float inv = 1.0f / fmaxf((float)deg, 1.0f);
    float4 r0 = *(const float4*)(rr + i * M + c);
    float4 r1 = *(const float4*)(rr + i * M + c + 4);
    float o[8];
    o[0] = fmaf(a[0], inv, r0.x); o[1] = fmaf(a[1], inv, r0.y);
    o[2] = fmaf(a[2], inv, r0.z); o[3] = fmaf(a[3], inv, r0.w);
    o[4] = fmaf(a[4], inv, r1.x); o[5] = fmaf(a[5], inv, r1.y);
    o[6] = fmaf(a[6], inv, r1.z); o[7] = fmaf(a[7], inv, r1.w);
    if (RELU) {
        #pragma unroll
        for (int q = 0; q < 8; ++q) o[q] = fmaxf(o[q], 0.f);
    }
    if (OUTBF16) {
        short4 lo4 = { f2bf(o[0]), f2bf(o[1]), f2bf(o[2]), f2bf(o[3]) };
        short4 hi4 = { f2bf(o[4]), f2bf(o[5]), f2bf(o[6]), f2bf(o[7]) };
        *(short4*)((short*)outp + i * M + c) = lo4;
        *(short4*)((short*)outp + i * M + c + 4) = hi4;
    } else {
        float4 lo4 = { o[0], o[1], o[2], o[3] };
        float4 hi4 = { o[4], o[5], o[6], o[7] };
        *(float4*)((float*)outp + i * M + c) = lo4;
        *(float4*)((float*)outp + i * M + c + 4) = hi4;
    }
}

extern "C" void kernel_launch(void* const* d_in, const int* in_sizes, int n_in,
                              void* d_out, int out_size, void* d_ws, size_t ws_size,
                              hipStream_t stream) {
    const float* x   = (const float*)d_in[0];
    const int*   ei  = (const int*)  d_in[1];
    const float* W1l = (const float*)d_in[2];
    const float* W1r = (const float*)d_in[3];
    const float* b1  = (const float*)d_in[4];
    const float* W2l = (const float*)d_in[5];
    const float* W2r = (const float*)d_in[6];
    const float* b2  = (const float*)d_in[7];
    float* out = (float*)d_out;

    const int N = in_sizes[0] / D_IN;
    const int E = in_sizes[1] / 2;
    const int* src = ei;
    const int* dst = ei + E;
    const int NB = (N + NPB - 1) / NPB;     // <= 256 (N <= 65536)

    // -------- workspace layout (~58 MB) --------
    short* xb   = (short*)d_ws;                       // [N*128] bf16 -> hb
    short* xlb  = xb + (size_t)N * 128;               // [N*128] bf16 -> hlb
    float* xr   = (float*)(xlb + (size_t)N * 128);    // [N*128] f32  -> hr
    short* wt1  = (short*)(xr + (size_t)N * 128);     // [256*128] bf16
    short* wt2  = wt1 + 256 * 128;                    // [128*128] bf16
    int* gh     = (int*)(wt2 + 128 * 128);            // [256]
    int* pbase  = gh + 256;                           // [257]
    int* pcur   = pbase + 257;                        // [256]
    int* cnt    = pcur + 256;                         // [N]
    int* beg    = cnt + N;                            // [N]
    int* pairs  = beg + N;                            // [E] packed (dLocal<<16|src)
    int* colArr = pairs + E;                          // [E]

    short* hb  = xb;
    short* hlb = xlb;
    float* hr  = xr;

    // -------- conversions --------
    conv_bf16<<<2048, 256, 0, stream>>>(x, xb, (long)N * 128 / 4);
    build_wt<<<(256 * 128 + 255) / 256, 256, 0, stream>>>(W1l, W1r, wt1, 128, 128);
    build_wt<<<(128 * 128 + 255) / 256, 256, 0, stream>>>(W2l, W2r, wt2, 64, 64);

    // -------- CSR build: two-level counting sort --------
    hipMemsetAsync(gh, 0, 256 * sizeof(int), stream);
    bucket_hist<<<512, 256, 0, stream>>>(dst, gh, E, NB);
    bucket_scan<<<1, 256, 0, stream>>>(gh, pbase, pcur, E, NB);
    bucket_fill<<<(E + CH - 1) / CH, 256, 0, stream>>>(src, dst, pcur, pairs, E, NB);
    node_fill<<<NB, 256, 0, stream>>>(pairs, pbase, cnt, beg, colArr, N);

    // -------- layer 1 --------
    gemm_dual<256, 128><<<(N + 63) / 64, 256, 0, stream>>>(xb, wt1, b1, xlb, xr, N);
    {
        long T = (long)N * (D_HID / 8);
        gather_agg<D_HID, true, true>
            <<<(int)((T + 255) / 256), 256, 0, stream>>>(xlb, xr, beg, cnt, colArr, hb, N);
    }

    // -------- layer 2 --------
    gemm_dual<128, 64><<<(N + 127) / 128, 256, 0, stream>>>(hb, wt2, b2, hlb, hr, N);
    {
        long T = (long)N * (D_OUT / 8);
        gather_agg<D_OUT, false, false>
            <<<(int)((T + 255) / 256), 256, 0, stream>>>(hlb, hr, beg, cnt, colArr, out, N);
    }
}